// Round 4
// baseline (676.573 us; speedup 1.0000x reference)
//
#include <hip/hip_runtime.h>
#include <hip/hip_bf16.h>

// CGCNN forward. Decomposition:
//   t[n,m,:] = hi_proj[n,:] + hj_proj[idx[n,m],:] + bond[n,m,:]@w_b  (bias folded into hi_proj)
// k_bond: bf16 MFMA GEMM; raw acc staged to LDS; hi/hj (bf16) added in a fully-coalesced
// writeout phase that also accumulates bn1 stats. LDS overlaid (wbT/t_lds, A_lds/red)
// -> 27.6KB/block -> 4 blocks/CU (was 47.6KB, ~2).
// Transcendentals via HW v_exp_f32/v_log_f32/v_rcp_f32.

#define NN 40000
#define MM 12
#define AA 64
#define LL 3
#define CC 128
#define F0C 92
#define NBOND (NN*MM)
#define EPSBN 1e-5f

#define G_BOND 1250     // k_bond blocks; 7500 tiles of 64 bonds -> 6 tiles/block
#define NTILE 7500
#define G_APPLY 1250    // k_apply blocks; 1250 groups of 32 sites -> 1 iter/block
#define RED_B 125       // stage-A reduction blocks

#define L2E 1.4426950408889634f
#define LN2 0.6931471805599453f

typedef __attribute__((ext_vector_type(8))) short bf16x8;
typedef __attribute__((ext_vector_type(4))) float f32x4;

__device__ __forceinline__ float softplusf_(float x) {
    float e = __builtin_amdgcn_exp2f(-fabsf(x) * L2E);
    return fmaxf(x, 0.f) + __builtin_amdgcn_logf(1.f + e) * LN2;
}
__device__ __forceinline__ float sigmoidf_(float x) {
    return __builtin_amdgcn_rcpf(1.f + __builtin_amdgcn_exp2f(-x * L2E));
}
__device__ __forceinline__ unsigned short f2bf(float f) {
    unsigned int u = __float_as_uint(f);
    unsigned int r = (u + 0x7fffu + ((u >> 16) & 1u)) >> 16;
    return (unsigned short)r;
}
__device__ __forceinline__ float bf2f(unsigned short s) {
    return __uint_as_float(((unsigned int)s) << 16);
}

// ---------------- bond features f32 -> bf16, once ----------------
__global__ __launch_bounds__(256) void k_cvt(const float* __restrict__ in,
        unsigned short* __restrict__ out) {
    size_t i = ((size_t)blockIdx.x * 256 + threadIdx.x) * 8;
    float4 a = *(const float4*)&in[i];
    float4 b = *(const float4*)&in[i + 4];
    ushort4 ua, ub;
    ua.x = f2bf(a.x); ua.y = f2bf(a.y); ua.z = f2bf(a.z); ua.w = f2bf(a.w);
    ub.x = f2bf(b.x); ub.y = f2bf(b.y); ub.z = f2bf(b.z); ub.w = f2bf(b.w);
    *(ushort4*)&out[i] = ua;
    *(ushort4*)&out[i + 4] = ub;
}

// ---------------- fc1: h = site @ fc1_w + fc1_b  (40000x92 @ 92x64) ----------------
__global__ __launch_bounds__(256) void k_fc1(const float* __restrict__ site,
        const float* __restrict__ w, const float* __restrict__ b,
        float* __restrict__ h) {
    __shared__ float w_s[F0C][AA];
    __shared__ float x_s[16][F0C];
    int tid = threadIdx.x;
    for (int i = tid; i < F0C * AA; i += 256) w_s[i / AA][i % AA] = w[i];
    int n0 = blockIdx.x * 16;
    for (int i = tid; i < 16 * F0C; i += 256) x_s[i / F0C][i % F0C] = site[(size_t)n0 * F0C + i];
    __syncthreads();
    int d = tid & 63, ng = tid >> 6;
    float bb = b[d];
    float acc[4] = {bb, bb, bb, bb};
    #pragma unroll 4
    for (int k = 0; k < F0C; ++k) {
        float wv = w_s[k][d];
        acc[0] += x_s[ng][k] * wv;
        acc[1] += x_s[ng + 4][k] * wv;
        acc[2] += x_s[ng + 8][k] * wv;
        acc[3] += x_s[ng + 12][k] * wv;
    }
    #pragma unroll
    for (int rr = 0; rr < 4; ++rr)
        h[(size_t)(n0 + ng + rr * 4) * AA + d] = acc[rr];
}

// ---------------- proj: hi = h@w_i + bias, hj = h@w_j -> bf16 ----------------
__global__ __launch_bounds__(256) void k_proj(const float* __restrict__ h,
        const float* __restrict__ convw, const float* __restrict__ convb,
        unsigned short* __restrict__ hi, unsigned short* __restrict__ hj) {
    __shared__ float w_s[64][256];   // cols 0..127 = w_i, 128..255 = w_j
    __shared__ float hT[64][36];     // transposed h tile [k][row]
    int tid = threadIdx.x;
    for (int i = tid; i < 64 * 256; i += 256) {
        int k = i >> 8, c = i & 255;
        w_s[k][c] = convw[(size_t)((c < 128 ? k : 64 + k)) * 128 + (c & 127)];
    }
    int row0 = blockIdx.x * 32;
    for (int i = tid; i < 2048; i += 256) {
        int r = i >> 6, k = i & 63;
        hT[k][r] = h[(size_t)(row0 + r) * 64 + k];
    }
    __syncthreads();
    int c0 = (tid & 63) * 4;
    int r0 = (tid >> 6) * 8;
    float acc[8][4];
    #pragma unroll
    for (int r = 0; r < 8; ++r)
        #pragma unroll
        for (int i = 0; i < 4; ++i) acc[r][i] = 0.f;
    #pragma unroll 4
    for (int k = 0; k < 64; ++k) {
        float4 w4 = *(const float4*)&w_s[k][c0];
        float4 ha = *(const float4*)&hT[k][r0];
        float4 hb = *(const float4*)&hT[k][r0 + 4];
        float wv[4] = {w4.x, w4.y, w4.z, w4.w};
        float hv[8] = {ha.x, ha.y, ha.z, ha.w, hb.x, hb.y, hb.z, hb.w};
        #pragma unroll
        for (int r = 0; r < 8; ++r)
            #pragma unroll
            for (int i = 0; i < 4; ++i) acc[r][i] += hv[r] * wv[i];
    }
    bool isHi = (c0 < 128);
    int cc = isHi ? c0 : c0 - 128;
    float4 cb4 = make_float4(0.f, 0.f, 0.f, 0.f);
    if (isHi) cb4 = *(const float4*)&convb[c0];
    unsigned short* dst = isHi ? hi : hj;
    #pragma unroll
    for (int r = 0; r < 8; ++r) {
        int n = row0 + r0 + r;
        ushort4 o;
        o.x = f2bf(acc[r][0] + cb4.x);
        o.y = f2bf(acc[r][1] + cb4.y);
        o.z = f2bf(acc[r][2] + cb4.z);
        o.w = f2bf(acc[r][3] + cb4.w);
        *(ushort4*)&dst[(size_t)n * 128 + cc] = o;
    }
}

// ---------------- bond GEMM (bf16 MFMA) + t assembly + bn1 partial stats ----------------
template<bool BFQ>
__global__ __launch_bounds__(256, 4) void k_bond(const float* __restrict__ bf,
        const unsigned short* __restrict__ bfq,
        const float* __restrict__ wb,
        const unsigned short* __restrict__ hi, const unsigned short* __restrict__ hj,
        const int* __restrict__ bidx,
        unsigned short* __restrict__ tbuf,
        float* __restrict__ part1) {
    // buf0: wbT [128][72] ushort (preload only) THEN t_lds [64][136] ushort
    // buf1: A_lds [64][72] ushort, THEN red [16][128] float
    __shared__ __align__(16) char buf0[128 * 72 * 2];
    __shared__ __align__(16) char buf1[64 * 72 * 2];
    auto wbT   = (unsigned short(*)[72])buf0;
    auto t_lds = (unsigned short(*)[136])buf0;
    auto A_lds = (unsigned short(*)[72])buf1;
    auto red   = (float(*)[128])buf1;

    int tid = threadIdx.x;
    int lane = tid & 63, w = tid >> 6;
    int l15 = lane & 15, l4 = lane >> 4;

    for (int i = tid; i < 64 * 128; i += 256) {
        int k = i >> 7, c = i & 127;
        wbT[c][k] = f2bf(wb[i]);
    }
    __syncthreads();

    bf16x8 bfr[2][8];
    #pragma unroll
    for (int kh = 0; kh < 2; ++kh)
        #pragma unroll
        for (int ct = 0; ct < 8; ++ct)
            bfr[kh][ct] = *(const bf16x8*)&wbT[ct * 16 + l15][kh * 32 + l4 * 8];

    // writeout-phase fixed coords
    int wc8 = (tid & 15) * 8;   // col block owned at writeout
    int wr  = tid >> 4;         // base row at writeout
    float suml[8], sql[8];
    #pragma unroll
    for (int k = 0; k < 8; ++k) { suml[k] = 0.f; sql[k] = 0.f; }

    for (int tile = blockIdx.x; tile < NTILE; tile += G_BOND) {
        int bond0 = tile * 64;
        __syncthreads();  // prev tile: t_lds reads + A_lds MFMA reads done
        if constexpr (BFQ) {
            int r = tid >> 3, c8 = (tid & 7) * 8;
            #pragma unroll
            for (int rr = 0; rr < 2; ++rr) {
                bf16x8 v = *(const bf16x8*)&bfq[((size_t)(bond0 + r + rr * 32)) * 64 + c8];
                *(bf16x8*)&A_lds[r + rr * 32][c8] = v;
            }
        } else {
            int r = tid >> 4, kq = (tid & 15) * 4;
            #pragma unroll
            for (int rr = 0; rr < 4; ++rr) {
                float4 v = *(const float4*)&bf[((size_t)(bond0 + r + rr * 16)) * 64 + kq];
                ushort4 u;
                u.x = f2bf(v.x); u.y = f2bf(v.y); u.z = f2bf(v.z); u.w = f2bf(v.w);
                *(ushort4*)&A_lds[r + rr * 16][kq] = u;
            }
        }
        __syncthreads();

        f32x4 acc[8];
        #pragma unroll
        for (int ct = 0; ct < 8; ++ct) acc[ct] = (f32x4){0.f, 0.f, 0.f, 0.f};
        #pragma unroll
        for (int kh = 0; kh < 2; ++kh) {
            bf16x8 a = *(const bf16x8*)&A_lds[w * 16 + l15][kh * 32 + l4 * 8];
            #pragma unroll
            for (int ct = 0; ct < 8; ++ct)
                acc[ct] = __builtin_amdgcn_mfma_f32_16x16x32_bf16(a, bfr[kh][ct], acc[ct], 0, 0, 0);
        }

        // stage raw GEMM result (bf16) into t_lds
        int rbase = w * 16 + l4 * 4;
        #pragma unroll
        for (int reg = 0; reg < 4; ++reg)
            #pragma unroll
            for (int ct = 0; ct < 8; ++ct)
                t_lds[rbase + reg][ct * 16 + l15] = f2bf(acc[ct][reg]);
        __syncthreads();

        // writeout: coalesced hi/hj gather-add + stats + tbuf store
        #pragma unroll
        for (int rr = 0; rr < 4; ++rr) {
            int r = wr + rr * 16;
            int bond = bond0 + r;
            int n = bond / MM;
            int j = bidx[bond];
            bf16x8 g8  = *(const bf16x8*)&t_lds[r][wc8];
            bf16x8 hi8 = *(const bf16x8*)&hi[(size_t)n * 128 + wc8];
            bf16x8 hj8 = *(const bf16x8*)&hj[(size_t)j * 128 + wc8];
            bf16x8 o;
            #pragma unroll
            for (int k = 0; k < 8; ++k) {
                float t = bf2f((unsigned short)g8[k]) + bf2f((unsigned short)hi8[k])
                        + bf2f((unsigned short)hj8[k]);
                suml[k] += t;
                sql[k] += t * t;
                o[k] = (short)f2bf(t);
            }
            *(bf16x8*)&tbuf[(size_t)bond * 128 + wc8] = o;
        }
    }

    // block-level stats reduce: red[16][128] overlays A_lds (dead after last MFMA)
    __syncthreads();
    #pragma unroll
    for (int k = 0; k < 8; ++k) red[wr][wc8 + k] = suml[k];
    __syncthreads();
    if (tid < 128) {
        float s = 0.f;
        #pragma unroll
        for (int g = 0; g < 16; ++g) s += red[g][tid];
        part1[(size_t)blockIdx.x * 256 + tid] = s;
    }
    __syncthreads();
    #pragma unroll
    for (int k = 0; k < 8; ++k) red[wr][wc8 + k] = sql[k];
    __syncthreads();
    if (tid < 128) {
        float s = 0.f;
        #pragma unroll
        for (int g = 0; g < 16; ++g) s += red[g][tid];
        part1[(size_t)blockIdx.x * 256 + 128 + tid] = s;
    }
}

// ---------------- stage-A reductions ----------------
__global__ __launch_bounds__(256) void k_red1(const float* __restrict__ in, float* __restrict__ out) {
    int tid = threadIdx.x, b = blockIdx.x;
    float acc = 0.f;
    for (int r = b * 10; r < b * 10 + 10; ++r) acc += in[(size_t)r * 256 + tid];
    out[(size_t)b * 256 + tid] = acc;
}
__global__ __launch_bounds__(128) void k_red2(const float* __restrict__ in, float* __restrict__ out) {
    int tid = threadIdx.x, b = blockIdx.x;
    float acc = 0.f;
    for (int r = b * 10; r < b * 10 + 10; ++r) acc += in[(size_t)r * 128 + tid];
    out[(size_t)b * 128 + tid] = acc;
}

// ---------------- finalize bn1 ----------------
__global__ __launch_bounds__(256) void k_fin1(const float* __restrict__ partA, const float* __restrict__ g,
                       const float* __restrict__ b, float* __restrict__ scsh) {
    __shared__ float sm[256];
    int tid = threadIdx.x;
    float acc = 0.f;
    for (int r = 0; r < RED_B; ++r) acc += partA[(size_t)r * 256 + tid];
    sm[tid] = acc;
    __syncthreads();
    if (tid < 128) {
        float m = sm[tid] / (float)NBOND;
        float v = sm[128 + tid] / (float)NBOND - m * m;
        float sc = g[tid] * rsqrtf(v + EPSBN);
        scsh[tid] = sc;
        scsh[128 + tid] = b[tid] - m * sc;
    }
}

// ---------------- finalize bn2 ----------------
__global__ __launch_bounds__(128) void k_fin2(const float* __restrict__ partB, const float* __restrict__ g,
                       const float* __restrict__ b, float* __restrict__ scsh2) {
    __shared__ float sm[128];
    int tid = threadIdx.x;
    float acc = 0.f;
    for (int r = 0; r < RED_B; ++r) acc += partB[(size_t)r * 128 + tid];
    sm[tid] = acc;
    __syncthreads();
    if (tid < 64) {
        float m = sm[tid] / (float)NN;
        float v = sm[64 + tid] / (float)NN - m * m;
        float sc = g[tid] * rsqrtf(v + EPSBN);
        scsh2[tid] = sc;
        scsh2[64 + tid] = b[tid] - m * sc;
    }
}

// ---------------- apply bn1 + gated sum over m + bn2 partial stats ----------------
__global__ __launch_bounds__(256) void k_apply(const unsigned short* __restrict__ tbuf,
        const float* __restrict__ scsh, float* __restrict__ s_out,
        float* __restrict__ part2) {
    __shared__ float red[32][64];
    int tid = threadIdx.x;
    int c8 = (tid & 7) * 8, sg = tid >> 3;
    float scf[8], shf[8], scc[8], shc[8];
    #pragma unroll
    for (int j = 0; j < 8; ++j) {
        scf[j] = scsh[c8 + j];       shf[j] = scsh[128 + c8 + j];
        scc[j] = scsh[64 + c8 + j];  shc[j] = scsh[192 + c8 + j];
    }
    float sum[8], sq[8];
    #pragma unroll
    for (int j = 0; j < 8; ++j) { sum[j] = 0.f; sq[j] = 0.f; }
    for (int q = blockIdx.x; q < NN / 32; q += G_APPLY) {
        int n = q * 32 + sg;
        const unsigned short* tb = tbuf + (size_t)n * (MM * 128);
        float sacc[8];
        #pragma unroll
        for (int j = 0; j < 8; ++j) sacc[j] = 0.f;
        #pragma unroll
        for (int m = 0; m < MM; ++m) {
            bf16x8 f8 = *(const bf16x8*)&tb[m * 128 + c8];
            bf16x8 s8 = *(const bf16x8*)&tb[m * 128 + 64 + c8];
            #pragma unroll
            for (int j = 0; j < 8; ++j) {
                float ff = bf2f((unsigned short)f8[j]);
                float ss = bf2f((unsigned short)s8[j]);
                sacc[j] += sigmoidf_(scf[j] * ff + shf[j]) * softplusf_(scc[j] * ss + shc[j]);
            }
        }
        float4 oa = make_float4(sacc[0], sacc[1], sacc[2], sacc[3]);
        float4 ob = make_float4(sacc[4], sacc[5], sacc[6], sacc[7]);
        *(float4*)&s_out[(size_t)n * 64 + c8] = oa;
        *(float4*)&s_out[(size_t)n * 64 + c8 + 4] = ob;
        #pragma unroll
        for (int j = 0; j < 8; ++j) { sum[j] += sacc[j]; sq[j] += sacc[j] * sacc[j]; }
    }
    #pragma unroll
    for (int j = 0; j < 8; ++j) red[sg][c8 + j] = sum[j];
    __syncthreads();
    if (tid < 64) {
        float t = 0.f;
        #pragma unroll
        for (int g = 0; g < 32; ++g) t += red[g][tid];
        part2[(size_t)blockIdx.x * 128 + tid] = t;
    }
    __syncthreads();
    #pragma unroll
    for (int j = 0; j < 8; ++j) red[sg][c8 + j] = sq[j];
    __syncthreads();
    if (tid < 64) {
        float t = 0.f;
        #pragma unroll
        for (int g = 0; g < 32; ++g) t += red[g][tid];
        part2[(size_t)blockIdx.x * 128 + 64 + tid] = t;
    }
}

// ---------------- h = softplus(h + bn2(s)) ----------------
__global__ __launch_bounds__(256) void k_upd(float* __restrict__ h, const float* __restrict__ s,
        const float* __restrict__ scsh2) {
    size_t i = ((size_t)blockIdx.x * 256 + threadIdx.x) * 4;
    int c0 = (int)(i & 63);
    float4 hv = *(const float4*)&h[i];
    float4 sv = *(const float4*)&s[i];
    float4 o;
    o.x = softplusf_(hv.x + scsh2[c0 + 0] * sv.x + scsh2[64 + c0 + 0]);
    o.y = softplusf_(hv.y + scsh2[c0 + 1] * sv.y + scsh2[64 + c0 + 1]);
    o.z = softplusf_(hv.z + scsh2[c0 + 2] * sv.z + scsh2[64 + c0 + 2]);
    o.w = softplusf_(hv.w + scsh2[c0 + 3] * sv.w + scsh2[64 + c0 + 3]);
    *(float4*)&h[i] = o;
}

// ---------------- pooling ----------------
__device__ __forceinline__ int lbound(const int* a, int n, int v) {
    int lo = 0, hi = n;
    while (lo < hi) { int mid = (lo + hi) >> 1; if (a[mid] < v) lo = mid + 1; else hi = mid; }
    return lo;
}

__global__ __launch_bounds__(256) void k_pool(const float* __restrict__ h,
        const int* __restrict__ cidx, float* __restrict__ feats) {
    __shared__ float red[4][68];
    __shared__ int bounds[2];
    int c = blockIdx.x, tid = threadIdx.x;
    if (tid == 0) {
        bounds[0] = lbound(cidx, NN, c);
        bounds[1] = lbound(cidx, NN, c + 1);
    }
    __syncthreads();
    int lo = bounds[0], hi = bounds[1];
    int d = tid & 63, g = tid >> 6;
    float acc = 0;
    for (int n = lo + g; n < hi; n += 4) acc += h[(size_t)n * 64 + d];
    red[g][d] = acc;
    __syncthreads();
    if (tid < 64) {
        float t = red[0][tid] + red[1][tid] + red[2][tid] + red[3][tid];
        int cnt = hi - lo;
        feats[(size_t)c * 65 + tid] = t / (float)(cnt > 0 ? cnt : 1);
    }
}

// ---------------- head ----------------
__global__ __launch_bounds__(128) void k_head1(float* __restrict__ feats, const float* __restrict__ fap,
        const float* __restrict__ g, const float* __restrict__ b, float* __restrict__ featsp) {
    int tid = threadIdx.x;
    if (tid < CC) feats[(size_t)tid * 65 + 64] = fap[tid];
    __syncthreads();
    if (tid < 65) {
        float s = 0;
        for (int r = 0; r < CC; ++r) s += feats[r * 65 + tid];
        float m = s / (float)CC;
        float v = 0;
        for (int r = 0; r < CC; ++r) { float d = feats[r * 65 + tid] - m; v += d * d; }
        v /= (float)CC;
        float sc = g[tid] * rsqrtf(v + EPSBN);
        float sh = b[tid] - m * sc;
        for (int r = 0; r < CC; ++r)
            featsp[r * 65 + tid] = softplusf_(sc * feats[r * 65 + tid] + sh);
    }
}

__global__ __launch_bounds__(128) void k_head2(const float* __restrict__ featsp,
        const float* __restrict__ fc2w, const float* __restrict__ fc2b,
        const float* __restrict__ fc3w, const float* __restrict__ fc3b,
        float* __restrict__ out) {
    __shared__ float fr[65];
    __shared__ float red[128];
    int r = blockIdx.x, tid = threadIdx.x;
    if (tid < 65) fr[tid] = featsp[(size_t)r * 65 + tid];
    __syncthreads();
    float acc = fc2b[tid];
    for (int k = 0; k < 65; ++k) acc += fr[k] * fc2w[k * 128 + tid];
    red[tid] = softplusf_(acc) * fc3w[tid];
    __syncthreads();
    for (int st = 64; st > 0; st >>= 1) {
        if (tid < st) red[tid] += red[tid + st];
        __syncthreads();
    }
    if (tid == 0) out[r] = red[0] + fc3b[0];
}

extern "C" void kernel_launch(void* const* d_in, const int* in_sizes, int n_in,
                              void* d_out, int out_size, void* d_ws, size_t ws_size,
                              hipStream_t stream) {
    const float* site  = (const float*)d_in[0];
    const float* bondf = (const float*)d_in[1];
    const float* fap   = (const float*)d_in[2];
    const float* fc1w  = (const float*)d_in[3];
    const float* fc1b  = (const float*)d_in[4];
    const float* convw = (const float*)d_in[5];
    const float* convb = (const float*)d_in[6];
    const float* bn1g  = (const float*)d_in[7];
    const float* bn1b  = (const float*)d_in[8];
    const float* bn2g  = (const float*)d_in[9];
    const float* bn2b  = (const float*)d_in[10];
    const float* topg  = (const float*)d_in[11];
    const float* topb  = (const float*)d_in[12];
    const float* fc2w  = (const float*)d_in[13];
    const float* fc2b  = (const float*)d_in[14];
    const float* fc3w  = (const float*)d_in[15];
    const float* fc3b  = (const float*)d_in[16];
    const int*   bidx  = (const int*)d_in[17];
    const int*   cidx  = (const int*)d_in[18];
    float* out = (float*)d_out;

    char* w = (char*)d_ws;
    constexpr size_t SZ_H  = (size_t)NN * 64 * 4;
    constexpr size_t SZ_HP = (size_t)NN * 128 * 2;   // hi/hj bf16
    constexpr size_t OFF_H  = 0;
    constexpr size_t OFF_HI = OFF_H + SZ_H;
    constexpr size_t OFF_HJ = OFF_HI + SZ_HP;
    constexpr size_t OFF_S  = OFF_HJ + SZ_HP;
    constexpr size_t OFF_SCSH1 = OFF_S + SZ_H;
    constexpr size_t OFF_SCSH2 = OFF_SCSH1 + 1024;
    constexpr size_t OFF_P1 = OFF_SCSH2 + 512;
    constexpr size_t OFF_P2 = OFF_P1 + (size_t)G_BOND * 256 * 4;
    constexpr size_t OFF_PA = OFF_P2 + (size_t)G_APPLY * 128 * 4;
    constexpr size_t OFF_PB = OFF_PA + (size_t)RED_B * 256 * 4;
    constexpr size_t OFF_FE = OFF_PB + (size_t)RED_B * 128 * 4;
    constexpr size_t OFF_FP = OFF_FE + 128 * 65 * 4;
    constexpr size_t OFF_T  = ((OFF_FP + 128 * 65 * 4) + 255) & ~(size_t)255;
    constexpr size_t OFF_BFQ = OFF_T + (size_t)NBOND * 128 * 2;
    constexpr size_t NEED_BFQ = OFF_BFQ + (size_t)NBOND * 64 * 2;

    float* h      = (float*)(w + OFF_H);
    unsigned short* hi = (unsigned short*)(w + OFF_HI);
    unsigned short* hj = (unsigned short*)(w + OFF_HJ);
    float* sbuf   = (float*)(w + OFF_S);
    float* scsh1  = (float*)(w + OFF_SCSH1);
    float* scsh2  = (float*)(w + OFF_SCSH2);
    float* part1  = (float*)(w + OFF_P1);
    float* part2  = (float*)(w + OFF_P2);
    float* partA  = (float*)(w + OFF_PA);
    float* partB  = (float*)(w + OFF_PB);
    float* feats  = (float*)(w + OFF_FE);
    float* featsp = (float*)(w + OFF_FP);
    unsigned short* tbuf = (unsigned short*)(w + OFF_T);
    unsigned short* bfq  = (unsigned short*)(w + OFF_BFQ);

    const bool useq = (ws_size >= NEED_BFQ);

    if (useq) k_cvt<<<NBOND * 64 / (256 * 8), 256, 0, stream>>>(bondf, bfq);
    k_fc1<<<2500, 256, 0, stream>>>(site, fc1w, fc1b, h);
    for (int l = 0; l < LL; ++l) {
        const float* cw = convw + (size_t)l * 192 * 128;
        const float* cb = convb + l * 128;
        k_proj<<<1250, 256, 0, stream>>>(h, cw, cb, hi, hj);
        if (useq)
            k_bond<true><<<G_BOND, 256, 0, stream>>>(bondf, bfq, cw + 128 * 128, hi, hj, bidx, tbuf, part1);
        else
            k_bond<false><<<G_BOND, 256, 0, stream>>>(bondf, bfq, cw + 128 * 128, hi, hj, bidx, tbuf, part1);
        k_red1<<<RED_B, 256, 0, stream>>>(part1, partA);
        k_fin1<<<1, 256, 0, stream>>>(partA, bn1g + l * 128, bn1b + l * 128, scsh1);
        k_apply<<<G_APPLY, 256, 0, stream>>>(tbuf, scsh1, sbuf, part2);
        k_red2<<<RED_B, 128, 0, stream>>>(part2, partB);
        k_fin2<<<1, 128, 0, stream>>>(partB, bn2g + l * 64, bn2b + l * 64, scsh2);
        k_upd<<<2500, 256, 0, stream>>>(h, sbuf, scsh2);
    }
    k_pool<<<128, 256, 0, stream>>>(h, cidx, feats);
    k_head1<<<1, 128, 0, stream>>>(feats, fap, topg, topb, featsp);
    k_head2<<<128, 128, 0, stream>>>(featsp, fc2w, fc2b, fc3w, fc3b, out);
}

// Round 5
// 557.830 us; speedup vs baseline: 1.2129x; 1.2129x over previous
//
#include <hip/hip_runtime.h>
#include <hip/hip_bf16.h>

// CGCNN forward, recompute-t structure (no t materialization):
//   t[n,m,:] = hi_proj[n,:] + hj_proj[idx[n,m],:] + bond[n,m,:]@w_b  (bias in hi_proj)
// k_stat: bf16 MFMA GEMM + gather, accumulates bn1 sum/sq only (no store).
// k_fuse: recomputes the same GEMM, applies bn1 + sigmoid*softplus in-register,
//         reduces over m within 192-bond (16-site) super-tiles, writes s + bn2 partials.
// Transcendentals via HW exp2/log/rcp. No __launch_bounds__ min-waves (r4 lesson:
// forcing 4 blocks/CU capped VGPR at 64 < bfr's 64+acc -> scratch spill regression).

#define NN 40000
#define MM 12
#define AA 64
#define LL 3
#define CC 128
#define F0C 92
#define NBOND (NN*MM)
#define EPSBN 1e-5f

#define G_BOND 1250     // k_stat blocks; 7500 tiles of 64 bonds -> 6 tiles/block
#define NTILE 7500
#define G_FUSE 1250     // k_fuse blocks; 2500 super-tiles of 192 bonds -> 2 iters/block
#define NSUPER 2500
#define RED_B 125

#define L2E 1.4426950408889634f
#define LN2 0.6931471805599453f

typedef __attribute__((ext_vector_type(8))) short bf16x8;
typedef __attribute__((ext_vector_type(4))) float f32x4;

__device__ __forceinline__ float softplusf_(float x) {
    float e = __builtin_amdgcn_exp2f(-fabsf(x) * L2E);
    return fmaxf(x, 0.f) + __builtin_amdgcn_logf(1.f + e) * LN2;
}
__device__ __forceinline__ float sigmoidf_(float x) {
    return __builtin_amdgcn_rcpf(1.f + __builtin_amdgcn_exp2f(-x * L2E));
}
__device__ __forceinline__ unsigned short f2bf(float f) {
    unsigned int u = __float_as_uint(f);
    unsigned int r = (u + 0x7fffu + ((u >> 16) & 1u)) >> 16;
    return (unsigned short)r;
}
__device__ __forceinline__ float bf2f(unsigned short s) {
    return __uint_as_float(((unsigned int)s) << 16);
}

// ---------------- bond features f32 -> bf16, once ----------------
__global__ __launch_bounds__(256) void k_cvt(const float* __restrict__ in,
        unsigned short* __restrict__ out) {
    size_t i = ((size_t)blockIdx.x * 256 + threadIdx.x) * 8;
    float4 a = *(const float4*)&in[i];
    float4 b = *(const float4*)&in[i + 4];
    ushort4 ua, ub;
    ua.x = f2bf(a.x); ua.y = f2bf(a.y); ua.z = f2bf(a.z); ua.w = f2bf(a.w);
    ub.x = f2bf(b.x); ub.y = f2bf(b.y); ub.z = f2bf(b.z); ub.w = f2bf(b.w);
    *(ushort4*)&out[i] = ua;
    *(ushort4*)&out[i + 4] = ub;
}

// ---------------- fc1 ----------------
__global__ __launch_bounds__(256) void k_fc1(const float* __restrict__ site,
        const float* __restrict__ w, const float* __restrict__ b,
        float* __restrict__ h) {
    __shared__ float w_s[F0C][AA];
    __shared__ float x_s[16][F0C];
    int tid = threadIdx.x;
    for (int i = tid; i < F0C * AA; i += 256) w_s[i / AA][i % AA] = w[i];
    int n0 = blockIdx.x * 16;
    for (int i = tid; i < 16 * F0C; i += 256) x_s[i / F0C][i % F0C] = site[(size_t)n0 * F0C + i];
    __syncthreads();
    int d = tid & 63, ng = tid >> 6;
    float bb = b[d];
    float acc[4] = {bb, bb, bb, bb};
    #pragma unroll 4
    for (int k = 0; k < F0C; ++k) {
        float wv = w_s[k][d];
        acc[0] += x_s[ng][k] * wv;
        acc[1] += x_s[ng + 4][k] * wv;
        acc[2] += x_s[ng + 8][k] * wv;
        acc[3] += x_s[ng + 12][k] * wv;
    }
    #pragma unroll
    for (int rr = 0; rr < 4; ++rr)
        h[(size_t)(n0 + ng + rr * 4) * AA + d] = acc[rr];
}

// ---------------- proj: hi = h@w_i + bias, hj = h@w_j -> bf16 ----------------
__global__ __launch_bounds__(256) void k_proj(const float* __restrict__ h,
        const float* __restrict__ convw, const float* __restrict__ convb,
        unsigned short* __restrict__ hi, unsigned short* __restrict__ hj) {
    __shared__ float w_s[64][256];
    __shared__ float hT[64][36];
    int tid = threadIdx.x;
    for (int i = tid; i < 64 * 256; i += 256) {
        int k = i >> 8, c = i & 255;
        w_s[k][c] = convw[(size_t)((c < 128 ? k : 64 + k)) * 128 + (c & 127)];
    }
    int row0 = blockIdx.x * 32;
    for (int i = tid; i < 2048; i += 256) {
        int r = i >> 6, k = i & 63;
        hT[k][r] = h[(size_t)(row0 + r) * 64 + k];
    }
    __syncthreads();
    int c0 = (tid & 63) * 4;
    int r0 = (tid >> 6) * 8;
    float acc[8][4];
    #pragma unroll
    for (int r = 0; r < 8; ++r)
        #pragma unroll
        for (int i = 0; i < 4; ++i) acc[r][i] = 0.f;
    #pragma unroll 4
    for (int k = 0; k < 64; ++k) {
        float4 w4 = *(const float4*)&w_s[k][c0];
        float4 ha = *(const float4*)&hT[k][r0];
        float4 hb = *(const float4*)&hT[k][r0 + 4];
        float wv[4] = {w4.x, w4.y, w4.z, w4.w};
        float hv[8] = {ha.x, ha.y, ha.z, ha.w, hb.x, hb.y, hb.z, hb.w};
        #pragma unroll
        for (int r = 0; r < 8; ++r)
            #pragma unroll
            for (int i = 0; i < 4; ++i) acc[r][i] += hv[r] * wv[i];
    }
    bool isHi = (c0 < 128);
    int cc = isHi ? c0 : c0 - 128;
    float4 cb4 = make_float4(0.f, 0.f, 0.f, 0.f);
    if (isHi) cb4 = *(const float4*)&convb[c0];
    unsigned short* dst = isHi ? hi : hj;
    #pragma unroll
    for (int r = 0; r < 8; ++r) {
        int n = row0 + r0 + r;
        ushort4 o;
        o.x = f2bf(acc[r][0] + cb4.x);
        o.y = f2bf(acc[r][1] + cb4.y);
        o.z = f2bf(acc[r][2] + cb4.z);
        o.w = f2bf(acc[r][3] + cb4.w);
        *(ushort4*)&dst[(size_t)n * 128 + cc] = o;
    }
}

// ---------------- pass 1: bn1 stats only (t computed in registers) ----------------
template<bool BFQ>
__global__ __launch_bounds__(256) void k_stat(const float* __restrict__ bf,
        const unsigned short* __restrict__ bfq,
        const float* __restrict__ wb,
        const unsigned short* __restrict__ hi, const unsigned short* __restrict__ hj,
        const int* __restrict__ bidx,
        float* __restrict__ part1) {
    __shared__ __align__(16) char buf0[128 * 72 * 2];  // wbT (preload), then red
    __shared__ __align__(16) char buf1[64 * 72 * 2];   // A_lds
    auto wbT   = (unsigned short(*)[72])buf0;
    auto red   = (float(*)[128])buf0;
    auto A_lds = (unsigned short(*)[72])buf1;

    int tid = threadIdx.x;
    int lane = tid & 63, w = tid >> 6;
    int l15 = lane & 15, l4 = lane >> 4;

    for (int i = tid; i < 64 * 128; i += 256) {
        int k = i >> 7, c = i & 127;
        wbT[c][k] = f2bf(wb[i]);
    }
    __syncthreads();

    bf16x8 bfr[2][8];
    #pragma unroll
    for (int kh = 0; kh < 2; ++kh)
        #pragma unroll
        for (int ct = 0; ct < 8; ++ct)
            bfr[kh][ct] = *(const bf16x8*)&wbT[ct * 16 + l15][kh * 32 + l4 * 8];

    float suml[8], sql[8];
    #pragma unroll
    for (int ct = 0; ct < 8; ++ct) { suml[ct] = 0.f; sql[ct] = 0.f; }

    int rbase = w * 16 + l4 * 4;
    for (int tile = blockIdx.x; tile < NTILE; tile += G_BOND) {
        int bond0 = tile * 64;
        __syncthreads();  // prev tile MFMA reads of A_lds done
        if constexpr (BFQ) {
            int r = tid >> 3, c8 = (tid & 7) * 8;
            #pragma unroll
            for (int rr = 0; rr < 2; ++rr) {
                bf16x8 v = *(const bf16x8*)&bfq[((size_t)(bond0 + r + rr * 32)) * 64 + c8];
                *(bf16x8*)&A_lds[r + rr * 32][c8] = v;
            }
        } else {
            int r = tid >> 4, kq = (tid & 15) * 4;
            #pragma unroll
            for (int rr = 0; rr < 4; ++rr) {
                float4 v = *(const float4*)&bf[((size_t)(bond0 + r + rr * 16)) * 64 + kq];
                ushort4 u;
                u.x = f2bf(v.x); u.y = f2bf(v.y); u.z = f2bf(v.z); u.w = f2bf(v.w);
                *(ushort4*)&A_lds[r + rr * 16][kq] = u;
            }
        }
        __syncthreads();

        f32x4 acc[8];
        #pragma unroll
        for (int ct = 0; ct < 8; ++ct) acc[ct] = (f32x4){0.f, 0.f, 0.f, 0.f};
        #pragma unroll
        for (int kh = 0; kh < 2; ++kh) {
            bf16x8 a = *(const bf16x8*)&A_lds[rbase - l4 * 4 + l15][kh * 32 + l4 * 8];
            #pragma unroll
            for (int ct = 0; ct < 8; ++ct)
                acc[ct] = __builtin_amdgcn_mfma_f32_16x16x32_bf16(a, bfr[kh][ct], acc[ct], 0, 0, 0);
        }

        #pragma unroll
        for (int reg = 0; reg < 4; ++reg) {
            int bond = bond0 + rbase + reg;
            int n = bond / MM;
            int j = bidx[bond];
            const unsigned short* hin = hi + (size_t)n * 128;
            const unsigned short* hjn = hj + (size_t)j * 128;
            #pragma unroll
            for (int ct = 0; ct < 8; ++ct) {
                int col = ct * 16 + l15;
                float t = acc[ct][reg] + bf2f(hin[col]) + bf2f(hjn[col]);
                suml[ct] += t;
                sql[ct] += t * t;
            }
        }
    }

    #pragma unroll
    for (int ct = 0; ct < 8; ++ct) {
        float s = suml[ct], q = sql[ct];
        s += __shfl_xor(s, 16); s += __shfl_xor(s, 32);
        q += __shfl_xor(q, 16); q += __shfl_xor(q, 32);
        suml[ct] = s; sql[ct] = q;
    }
    __syncthreads();   // wbT dead (bfr in regs); red overlays buf0
    if (l4 == 0) {
        #pragma unroll
        for (int ct = 0; ct < 8; ++ct) red[w][ct * 16 + l15] = suml[ct];
    }
    __syncthreads();
    if (tid < 128)
        part1[(size_t)blockIdx.x * 256 + tid] = red[0][tid] + red[1][tid] + red[2][tid] + red[3][tid];
    __syncthreads();
    if (l4 == 0) {
        #pragma unroll
        for (int ct = 0; ct < 8; ++ct) red[w][ct * 16 + l15] = sql[ct];
    }
    __syncthreads();
    if (tid < 128)
        part1[(size_t)blockIdx.x * 256 + 128 + tid] = red[0][tid] + red[1][tid] + red[2][tid] + red[3][tid];
}

// ---------------- pass 2: recompute t, bn1 + gate, m-reduce, bn2 partials ----------------
template<bool BFQ>
__global__ __launch_bounds__(256) void k_fuse(const float* __restrict__ bf,
        const unsigned short* __restrict__ bfq,
        const float* __restrict__ wb,
        const unsigned short* __restrict__ hi, const unsigned short* __restrict__ hj,
        const int* __restrict__ bidx,
        const float* __restrict__ scsh,
        float* __restrict__ s_out,
        float* __restrict__ part2) {
    __shared__ __align__(16) char buf0[192 * 68 * 2]; // wbT (preload), then val[192][68]
    __shared__ __align__(16) char buf1[64 * 72 * 2];  // A_lds, then red2[16][64]
    auto wbT   = (unsigned short(*)[72])buf0;
    auto val   = (unsigned short(*)[68])buf0;
    auto A_lds = (unsigned short(*)[72])buf1;
    auto red2  = (float(*)[64])buf1;

    int tid = threadIdx.x;
    int lane = tid & 63, w = tid >> 6;
    int l15 = lane & 15, l4 = lane >> 4;

    for (int i = tid; i < 64 * 128; i += 256) {
        int k = i >> 7, c = i & 127;
        wbT[c][k] = f2bf(wb[i]);
    }
    __syncthreads();

    bf16x8 bfr[2][8];
    #pragma unroll
    for (int kh = 0; kh < 2; ++kh)
        #pragma unroll
        for (int ct = 0; ct < 8; ++ct)
            bfr[kh][ct] = *(const bf16x8*)&wbT[ct * 16 + l15][kh * 32 + l4 * 8];

    // per-lane bn1 scale/shift for the 8 cols this lane owns (4 filt + 4 core)
    float scf[4], shf[4], scc[4], shc[4];
    #pragma unroll
    for (int ct = 0; ct < 4; ++ct) {
        int colA = ct * 16 + l15, colC = colA + 64;
        scf[ct] = scsh[colA];  shf[ct] = scsh[128 + colA];
        scc[ct] = scsh[colC];  shc[ct] = scsh[128 + colC];
    }

    // site-sum phase coords: thread owns (site = tid>>4, cols a0..a0+3)
    int ssite = tid >> 4, a0 = (tid & 15) * 4;
    float sum2[4] = {0, 0, 0, 0}, sq2[4] = {0, 0, 0, 0};

    int rbase = w * 16 + l4 * 4;
    for (int sup = blockIdx.x; sup < NSUPER; sup += G_FUSE) {
        int bond00 = sup * 192;
        #pragma unroll
        for (int sub = 0; sub < 3; ++sub) {
            int bond0 = bond00 + sub * 64;
            __syncthreads();  // A_lds free; (sub==0) val reads of prev super done
            if constexpr (BFQ) {
                int r = tid >> 3, c8 = (tid & 7) * 8;
                #pragma unroll
                for (int rr = 0; rr < 2; ++rr) {
                    bf16x8 v = *(const bf16x8*)&bfq[((size_t)(bond0 + r + rr * 32)) * 64 + c8];
                    *(bf16x8*)&A_lds[r + rr * 32][c8] = v;
                }
            } else {
                int r = tid >> 4, kq = (tid & 15) * 4;
                #pragma unroll
                for (int rr = 0; rr < 4; ++rr) {
                    float4 v = *(const float4*)&bf[((size_t)(bond0 + r + rr * 16)) * 64 + kq];
                    ushort4 u;
                    u.x = f2bf(v.x); u.y = f2bf(v.y); u.z = f2bf(v.z); u.w = f2bf(v.w);
                    *(ushort4*)&A_lds[r + rr * 16][kq] = u;
                }
            }
            __syncthreads();

            f32x4 acc[8];
            #pragma unroll
            for (int ct = 0; ct < 8; ++ct) acc[ct] = (f32x4){0.f, 0.f, 0.f, 0.f};
            #pragma unroll
            for (int kh = 0; kh < 2; ++kh) {
                bf16x8 a = *(const bf16x8*)&A_lds[w * 16 + l15][kh * 32 + l4 * 8];
                #pragma unroll
                for (int ct = 0; ct < 8; ++ct)
                    acc[ct] = __builtin_amdgcn_mfma_f32_16x16x32_bf16(a, bfr[kh][ct], acc[ct], 0, 0, 0);
            }

            // epilogue: t = acc + hi + hj; val = sigmoid(bn(filt)) * softplus(bn(core))
            #pragma unroll
            for (int reg = 0; reg < 4; ++reg) {
                int r = rbase + reg;
                int bond = bond0 + r;
                int n = bond / MM;
                int j = bidx[bond];
                const unsigned short* hin = hi + (size_t)n * 128;
                const unsigned short* hjn = hj + (size_t)j * 128;
                #pragma unroll
                for (int ct = 0; ct < 4; ++ct) {
                    int colA = ct * 16 + l15, colC = colA + 64;
                    float tA = acc[ct][reg]     + bf2f(hin[colA]) + bf2f(hjn[colA]);
                    float tC = acc[ct + 4][reg] + bf2f(hin[colC]) + bf2f(hjn[colC]);
                    float v = sigmoidf_(scf[ct] * tA + shf[ct])
                            * softplusf_(scc[ct] * tC + shc[ct]);
                    val[sub * 64 + r][colA] = f2bf(v);
                }
            }
        }
        __syncthreads();  // val complete for all 192 rows

        // site-sum: 16 sites x 64 cols; thread -> (ssite, a0..a0+3), 12 rows each
        float sv[4] = {0, 0, 0, 0};
        #pragma unroll
        for (int m = 0; m < MM; ++m) {
            ushort4 u = *(const ushort4*)&val[ssite * MM + m][a0];
            sv[0] += bf2f(u.x); sv[1] += bf2f(u.y);
            sv[2] += bf2f(u.z); sv[3] += bf2f(u.w);
        }
        int gsite = sup * 16 + ssite;
        *(float4*)&s_out[(size_t)gsite * 64 + a0] = make_float4(sv[0], sv[1], sv[2], sv[3]);
        #pragma unroll
        for (int k = 0; k < 4; ++k) { sum2[k] += sv[k]; sq2[k] += sv[k] * sv[k]; }
    }

    // block reduce bn2 partials: red2[16][64] overlays A_lds
    __syncthreads();
    #pragma unroll
    for (int k = 0; k < 4; ++k) red2[ssite][a0 + k] = sum2[k];
    __syncthreads();
    if (tid < 64) {
        float t = 0.f;
        #pragma unroll
        for (int g = 0; g < 16; ++g) t += red2[g][tid];
        part2[(size_t)blockIdx.x * 128 + tid] = t;
    }
    __syncthreads();
    #pragma unroll
    for (int k = 0; k < 4; ++k) red2[ssite][a0 + k] = sq2[k];
    __syncthreads();
    if (tid < 64) {
        float t = 0.f;
        #pragma unroll
        for (int g = 0; g < 16; ++g) t += red2[g][tid];
        part2[(size_t)blockIdx.x * 128 + 64 + tid] = t;
    }
}

// ---------------- stage-A reductions ----------------
__global__ __launch_bounds__(256) void k_red1(const float* __restrict__ in, float* __restrict__ out) {
    int tid = threadIdx.x, b = blockIdx.x;
    float acc = 0.f;
    for (int r = b * 10; r < b * 10 + 10; ++r) acc += in[(size_t)r * 256 + tid];
    out[(size_t)b * 256 + tid] = acc;
}
__global__ __launch_bounds__(128) void k_red2(const float* __restrict__ in, float* __restrict__ out) {
    int tid = threadIdx.x, b = blockIdx.x;
    float acc = 0.f;
    for (int r = b * 10; r < b * 10 + 10; ++r) acc += in[(size_t)r * 128 + tid];
    out[(size_t)b * 128 + tid] = acc;
}

// ---------------- finalize bn1 ----------------
__global__ __launch_bounds__(256) void k_fin1(const float* __restrict__ partA, const float* __restrict__ g,
                       const float* __restrict__ b, float* __restrict__ scsh) {
    __shared__ float sm[256];
    int tid = threadIdx.x;
    float acc = 0.f;
    for (int r = 0; r < RED_B; ++r) acc += partA[(size_t)r * 256 + tid];
    sm[tid] = acc;
    __syncthreads();
    if (tid < 128) {
        float m = sm[tid] / (float)NBOND;
        float v = sm[128 + tid] / (float)NBOND - m * m;
        float sc = g[tid] * rsqrtf(v + EPSBN);
        scsh[tid] = sc;
        scsh[128 + tid] = b[tid] - m * sc;
    }
}

// ---------------- finalize bn2 ----------------
__global__ __launch_bounds__(128) void k_fin2(const float* __restrict__ partB, const float* __restrict__ g,
                       const float* __restrict__ b, float* __restrict__ scsh2) {
    __shared__ float sm[128];
    int tid = threadIdx.x;
    float acc = 0.f;
    for (int r = 0; r < RED_B; ++r) acc += partB[(size_t)r * 128 + tid];
    sm[tid] = acc;
    __syncthreads();
    if (tid < 64) {
        float m = sm[tid] / (float)NN;
        float v = sm[64 + tid] / (float)NN - m * m;
        float sc = g[tid] * rsqrtf(v + EPSBN);
        scsh2[tid] = sc;
        scsh2[64 + tid] = b[tid] - m * sc;
    }
}

// ---------------- h = softplus(h + bn2(s)) ----------------
__global__ __launch_bounds__(256) void k_upd(float* __restrict__ h, const float* __restrict__ s,
        const float* __restrict__ scsh2) {
    size_t i = ((size_t)blockIdx.x * 256 + threadIdx.x) * 4;
    int c0 = (int)(i & 63);
    float4 hv = *(const float4*)&h[i];
    float4 sv = *(const float4*)&s[i];
    float4 o;
    o.x = softplusf_(hv.x + scsh2[c0 + 0] * sv.x + scsh2[64 + c0 + 0]);
    o.y = softplusf_(hv.y + scsh2[c0 + 1] * sv.y + scsh2[64 + c0 + 1]);
    o.z = softplusf_(hv.z + scsh2[c0 + 2] * sv.z + scsh2[64 + c0 + 2]);
    o.w = softplusf_(hv.w + scsh2[c0 + 3] * sv.w + scsh2[64 + c0 + 3]);
    *(float4*)&h[i] = o;
}

// ---------------- pooling ----------------
__device__ __forceinline__ int lbound(const int* a, int n, int v) {
    int lo = 0, hi = n;
    while (lo < hi) { int mid = (lo + hi) >> 1; if (a[mid] < v) lo = mid + 1; else hi = mid; }
    return lo;
}

__global__ __launch_bounds__(256) void k_pool(const float* __restrict__ h,
        const int* __restrict__ cidx, float* __restrict__ feats) {
    __shared__ float red[4][68];
    __shared__ int bounds[2];
    int c = blockIdx.x, tid = threadIdx.x;
    if (tid == 0) {
        bounds[0] = lbound(cidx, NN, c);
        bounds[1] = lbound(cidx, NN, c + 1);
    }
    __syncthreads();
    int lo = bounds[0], hi = bounds[1];
    int d = tid & 63, g = tid >> 6;
    float acc = 0;
    for (int n = lo + g; n < hi; n += 4) acc += h[(size_t)n * 64 + d];
    red[g][d] = acc;
    __syncthreads();
    if (tid < 64) {
        float t = red[0][tid] + red[1][tid] + red[2][tid] + red[3][tid];
        int cnt = hi - lo;
        feats[(size_t)c * 65 + tid] = t / (float)(cnt > 0 ? cnt : 1);
    }
}

// ---------------- head ----------------
__global__ __launch_bounds__(128) void k_head1(float* __restrict__ feats, const float* __restrict__ fap,
        const float* __restrict__ g, const float* __restrict__ b, float* __restrict__ featsp) {
    int tid = threadIdx.x;
    if (tid < CC) feats[(size_t)tid * 65 + 64] = fap[tid];
    __syncthreads();
    if (tid < 65) {
        float s = 0;
        for (int r = 0; r < CC; ++r) s += feats[r * 65 + tid];
        float m = s / (float)CC;
        float v = 0;
        for (int r = 0; r < CC; ++r) { float d = feats[r * 65 + tid] - m; v += d * d; }
        v /= (float)CC;
        float sc = g[tid] * rsqrtf(v + EPSBN);
        float sh = b[tid] - m * sc;
        for (int r = 0; r < CC; ++r)
            featsp[r * 65 + tid] = softplusf_(sc * feats[r * 65 + tid] + sh);
    }
}

__global__ __launch_bounds__(128) void k_head2(const float* __restrict__ featsp,
        const float* __restrict__ fc2w, const float* __restrict__ fc2b,
        const float* __restrict__ fc3w, const float* __restrict__ fc3b,
        float* __restrict__ out) {
    __shared__ float fr[65];
    __shared__ float red[128];
    int r = blockIdx.x, tid = threadIdx.x;
    if (tid < 65) fr[tid] = featsp[(size_t)r * 65 + tid];
    __syncthreads();
    float acc = fc2b[tid];
    for (int k = 0; k < 65; ++k) acc += fr[k] * fc2w[k * 128 + tid];
    red[tid] = softplusf_(acc) * fc3w[tid];
    __syncthreads();
    for (int st = 64; st > 0; st >>= 1) {
        if (tid < st) red[tid] += red[tid + st];
        __syncthreads();
    }
    if (tid == 0) out[r] = red[0] + fc3b[0];
}

extern "C" void kernel_launch(void* const* d_in, const int* in_sizes, int n_in,
                              void* d_out, int out_size, void* d_ws, size_t ws_size,
                              hipStream_t stream) {
    const float* site  = (const float*)d_in[0];
    const float* bondf = (const float*)d_in[1];
    const float* fap   = (const float*)d_in[2];
    const float* fc1w  = (const float*)d_in[3];
    const float* fc1b  = (const float*)d_in[4];
    const float* convw = (const float*)d_in[5];
    const float* convb = (const float*)d_in[6];
    const float* bn1g  = (const float*)d_in[7];
    const float* bn1b  = (const float*)d_in[8];
    const float* bn2g  = (const float*)d_in[9];
    const float* bn2b  = (const float*)d_in[10];
    const float* topg  = (const float*)d_in[11];
    const float* topb  = (const float*)d_in[12];
    const float* fc2w  = (const float*)d_in[13];
    const float* fc2b  = (const float*)d_in[14];
    const float* fc3w  = (const float*)d_in[15];
    const float* fc3b  = (const float*)d_in[16];
    const int*   bidx  = (const int*)d_in[17];
    const int*   cidx  = (const int*)d_in[18];
    float* out = (float*)d_out;

    char* w = (char*)d_ws;
    constexpr size_t SZ_H  = (size_t)NN * 64 * 4;
    constexpr size_t SZ_HP = (size_t)NN * 128 * 2;   // hi/hj bf16
    constexpr size_t OFF_H  = 0;
    constexpr size_t OFF_HI = OFF_H + SZ_H;
    constexpr size_t OFF_HJ = OFF_HI + SZ_HP;
    constexpr size_t OFF_S  = OFF_HJ + SZ_HP;
    constexpr size_t OFF_SCSH1 = OFF_S + SZ_H;
    constexpr size_t OFF_SCSH2 = OFF_SCSH1 + 1024;
    constexpr size_t OFF_P1 = OFF_SCSH2 + 512;
    constexpr size_t OFF_P2 = OFF_P1 + (size_t)G_BOND * 256 * 4;
    constexpr size_t OFF_PA = OFF_P2 + (size_t)G_FUSE * 128 * 4;
    constexpr size_t OFF_PB = OFF_PA + (size_t)RED_B * 256 * 4;
    constexpr size_t OFF_FE = OFF_PB + (size_t)RED_B * 128 * 4;
    constexpr size_t OFF_FP = OFF_FE + 128 * 65 * 4;
    constexpr size_t OFF_BFQ = ((OFF_FP + 128 * 65 * 4) + 255) & ~(size_t)255;
    constexpr size_t NEED_BFQ = OFF_BFQ + (size_t)NBOND * 64 * 2;

    float* h      = (float*)(w + OFF_H);
    unsigned short* hi = (unsigned short*)(w + OFF_HI);
    unsigned short* hj = (unsigned short*)(w + OFF_HJ);
    float* sbuf   = (float*)(w + OFF_S);
    float* scsh1  = (float*)(w + OFF_SCSH1);
    float* scsh2  = (float*)(w + OFF_SCSH2);
    float* part1  = (float*)(w + OFF_P1);
    float* part2  = (float*)(w + OFF_P2);
    float* partA  = (float*)(w + OFF_PA);
    float* partB  = (float*)(w + OFF_PB);
    float* feats  = (float*)(w + OFF_FE);
    float* featsp = (float*)(w + OFF_FP);
    unsigned short* bfq = (unsigned short*)(w + OFF_BFQ);

    const bool useq = (ws_size >= NEED_BFQ);

    if (useq) k_cvt<<<NBOND * 64 / (256 * 8), 256, 0, stream>>>(bondf, bfq);
    k_fc1<<<2500, 256, 0, stream>>>(site, fc1w, fc1b, h);
    for (int l = 0; l < LL; ++l) {
        const float* cw = convw + (size_t)l * 192 * 128;
        const float* cb = convb + l * 128;
        k_proj<<<1250, 256, 0, stream>>>(h, cw, cb, hi, hj);
        if (useq) {
            k_stat<true><<<G_BOND, 256, 0, stream>>>(bondf, bfq, cw + 128 * 128, hi, hj, bidx, part1);
        } else {
            k_stat<false><<<G_BOND, 256, 0, stream>>>(bondf, bfq, cw + 128 * 128, hi, hj, bidx, part1);
        }
        k_red1<<<RED_B, 256, 0, stream>>>(part1, partA);
        k_fin1<<<1, 256, 0, stream>>>(partA, bn1g + l * 128, bn1b + l * 128, scsh1);
        if (useq) {
            k_fuse<true><<<G_FUSE, 256, 0, stream>>>(bondf, bfq, cw + 128 * 128, hi, hj, bidx, scsh1, sbuf, part2);
        } else {
            k_fuse<false><<<G_FUSE, 256, 0, stream>>>(bondf, bfq, cw + 128 * 128, hi, hj, bidx, scsh1, sbuf, part2);
        }
        k_red2<<<RED_B, 128, 0, stream>>>(part2, partB);
        k_fin2<<<1, 128, 0, stream>>>(partB, bn2g + l * 64, bn2b + l * 64, scsh2);
        k_upd<<<2500, 256, 0, stream>>>(h, sbuf, scsh2);
    }
    k_pool<<<128, 256, 0, stream>>>(h, cidx, feats);
    k_head1<<<1, 128, 0, stream>>>(feats, fap, topg, topb, featsp);
    k_head2<<<128, 128, 0, stream>>>(featsp, fc2w, fc2b, fc3w, fc3b, out);
}